// Round 6
// baseline (279.859 us; speedup 1.0000x reference)
//
#include <hip/hip_runtime.h>

// SSIM (skimage default): 7x7 uniform filter, valid crop (pad=3), sample cov.
// Images: 4096x4096 fp32, output region 4090x4090, result = mean(S) scalar.
//
// R6: attack the real bottleneck. R5's L3-hot replay (0.13 MB HBM) ran at the
// SAME 144 us as cold runs -> the kernel is VMEM-instruction/L1-throughput
// bound, not bandwidth/latency bound. R5 issued 16 dwordx2 loads per
// thread-row (8 KB through L1 per wave-row, 64 B/pixel, 4x halo over-read).
// R6: 4 output cols/thread via 3x float4 per image = 6 load-insts/row,
// 24 B/pixel (2.7x less L1 traffic), and fewer wave-rows (ROWS=18, halo
// 24/18 = 1.33x).
// State shrunk with the identity: SSIM needs only soo+stt (never soo, stt
// separately) -> 4 stats/window -> ring[6][16].
// SPILL LESSON (R2-R4): NEVER let the steady strip flatten. The jb-loop has
// a compile-time trip count, so force "#pragma unroll 1" on it; the
// unroll-6 body keeps ring slots compile-time. Tail strip (4 rows, only
// GY-1 blocks) uses the guarded path.
// Right edge: 2nd/3rd float4 clamped to col 4092 (no OOB, no row-wrap);
// invalid windows masked with cndmask (NOT 0*s: garbage can be NaN).

#define W_IMG   4096
#define H_IMG   4096
#define OW      4090
#define OH      4090
#define ROWS    18            // output rows per block strip (3 x unroll-6)
#define NTHR    256           // threads per block
#define CPB     1024          // output columns per block (4 per thread)
#define GX      4
#define GY      228           // 227*18 = 4086, tail strip = 4 rows
#define NBLK    (GX * GY)     // 912

// h/v layout: [0..3]=so(win0..3), [4..7]=st, [8..11]=soo+stt, [12..15]=sot
__device__ __forceinline__ void hsums4(const float* __restrict__ pO,
                                       const float* __restrict__ pT,
                                       int d1, int d2, float h[16])
{
    float4 A0 = *(const float4*)(pO);
    float4 A1 = *(const float4*)(pO + d1);
    float4 A2 = *(const float4*)(pO + d2);
    float4 B0 = *(const float4*)(pT);
    float4 B1 = *(const float4*)(pT + d1);
    float4 B2 = *(const float4*)(pT + d2);
    float o[12] = {A0.x,A0.y,A0.z,A0.w, A1.x,A1.y,A1.z,A1.w, A2.x,A2.y,A2.z,A2.w};
    float u[12] = {B0.x,B0.y,B0.z,B0.w, B1.x,B1.y,B1.z,B1.w, B2.x,B2.y,B2.z,B2.w};

    float pp[10], pc[10];
    #pragma unroll
    for (int k = 0; k < 10; k++) {
        pp[k] = fmaf(o[k], o[k], u[k]*u[k]);   // o^2 + t^2
        pc[k] = o[k] * u[k];                   // o*t
    }

    float so = ((o[0]+o[1])+(o[2]+o[3])) + ((o[4]+o[5])+o[6]);
    float st = ((u[0]+u[1])+(u[2]+u[3])) + ((u[4]+u[5])+u[6]);
    float sp = ((pp[0]+pp[1])+(pp[2]+pp[3])) + ((pp[4]+pp[5])+pp[6]);
    float sc = ((pc[0]+pc[1])+(pc[2]+pc[3])) + ((pc[4]+pc[5])+pc[6]);
    h[0] = so; h[4] = st; h[8] = sp; h[12] = sc;
    #pragma unroll
    for (int k = 1; k < 4; k++) {
        so = (so - o[k-1])  + o[k+6];   h[0+k]  = so;
        st = (st - u[k-1])  + u[k+6];   h[4+k]  = st;
        sp = (sp - pp[k-1]) + pp[k+6];  h[8+k]  = sp;
        sc = (sc - pc[k-1]) + pc[k+6];  h[12+k] = sc;
    }
}

__device__ __forceinline__ float ssim4(const float v[16], int k)
{
    const float m    = 1.0f / 49.0f;
    const float m2   = m * m;
    const float covn = 49.0f / 48.0f;
    const float cm   = covn * m;      // covn/49
    const float cm2  = covn * m2;     // covn/49^2
    const float C1   = 4.0e-4f;       // (0.01*2)^2
    const float C2   = 3.6e-3f;       // (0.03*2)^2

    float so  = v[k], st = v[4+k], spp = v[8+k], sot = v[12+k];
    float P   = so * st;
    float Q   = fmaf(so, so, st*st);
    float A1  = fmaf(2.0f*m2, P, C1);
    float B1  = fmaf(m2, Q, C1);
    float A2  = fmaf(2.0f*cm, sot, fmaf(-2.0f*cm2, P, C2));
    float B2  = fmaf(cm, spp, fmaf(-cm2, Q, C2));
    return (A1*A2) * __builtin_amdgcn_rcpf(B1*B2);  // ~1 ulp, within tol
}

// One steady step, ring slot S compile-time. v covers rows [j..j+5] on entry;
// add new row j+6, emit 4 (masked) pixels, retire row j from ring[S].
#define SSTEP(S)                                                             \
    {                                                                        \
        float h[16];                                                         \
        hsums4(pO, pT, d1, d2, h);                                           \
        pO += W_IMG; pT += W_IMG;                                            \
        _Pragma("unroll") for (int q = 0; q < 16; q++) v[q] += h[q];         \
        float s0 = ssim4(v,0), s1 = ssim4(v,1), s2 = ssim4(v,2), s3 = ssim4(v,3); \
        acc += m0 ? s0 : 0.0f;                                               \
        acc += m1 ? s1 : 0.0f;                                               \
        acc += m2 ? s2 : 0.0f;                                               \
        acc += m3 ? s3 : 0.0f;                                               \
        _Pragma("unroll") for (int q = 0; q < 16; q++) v[q] -= ring[S][q];   \
        _Pragma("unroll") for (int q = 0; q < 16; q++) ring[S][q] = h[q];    \
    }

__global__ __launch_bounds__(NTHR, 2)
void ssim_main(const float* __restrict__ O, const float* __restrict__ T,
               float* __restrict__ accp, unsigned* __restrict__ ctr,
               float* __restrict__ out)
{
    const int t  = threadIdx.x;
    const int c0 = blockIdx.x * CPB + 4 * t;   // first of 4 output cols (%4==0)
    const int r0 = blockIdx.y * ROWS;
    const int rows_in = min(ROWS, OH - r0);

    // right-edge clamps: loads never pass col 4095, never wrap a row
    const int d1 = min(c0 + 4, W_IMG - 4) - c0;
    const int d2 = min(c0 + 8, W_IMG - 4) - c0;
    const bool m0 = (c0 + 0) < OW;
    const bool m1 = (c0 + 1) < OW;
    const bool m2 = (c0 + 2) < OW;
    const bool m3 = (c0 + 3) < OW;

    float acc = 0.0f;

    const float* pO = O + (size_t)r0 * W_IMG + c0;
    const float* pT = T + (size_t)r0 * W_IMG + c0;

    float ring[6][16];   // 6-row delay line of window sums (VGPRs)
    float v[16];         // running 7-row vertical sums
    #pragma unroll
    for (int q = 0; q < 16; q++) v[q] = 0.0f;

    // warm-up: input rows r0 .. r0+5 into slots 0..5
    #pragma unroll
    for (int i = 0; i < 6; i++) {
        float h[16];
        hsums4(pO, pT, d1, d2, h);
        pO += W_IMG; pT += W_IMG;
        #pragma unroll
        for (int q = 0; q < 16; q++) { v[q] += h[q]; ring[i][q] = h[q]; }
    }

    if (rows_in == ROWS) {
        // steady: 3 runtime iterations (DO NOT UNROLL - flattening the strip
        // explodes live ranges and spills the ring: R2-R4, 400-700 MB scratch)
        #pragma unroll 1
        for (int jb = 0; jb < 3; ++jb) {
            SSTEP(0) SSTEP(1) SSTEP(2) SSTEP(3) SSTEP(4) SSTEP(5)
        }
    } else {
        // tail strip (4 rows; GY-1 blocks only): guarded, slots compile-time
        #pragma unroll 1
        for (int jb = 0; jb < ROWS; jb += 6) {
            #pragma unroll
            for (int u = 0; u < 6; ++u) {
                if (jb + u < rows_in) { SSTEP(u) }
            }
        }
    }

    // wave(64) shuffle reduction
    #pragma unroll
    for (int off = 32; off; off >>= 1) acc += __shfl_down(acc, off);

    __shared__ float wpart[NTHR / 64];
    if ((t & 63) == 0) wpart[t >> 6] = acc;
    __syncthreads();
    if (t == 0) {
        float s = 0.0f;
        #pragma unroll
        for (int w = 0; w < NTHR / 64; w++) s += wpart[w];
        atomicAdd(accp, s);               // device-scope
        __threadfence();
        unsigned prev = atomicAdd(ctr, 1u);
        if (prev == NBLK - 1) {           // last block finalizes
            __threadfence();
            float tot = atomicAdd(accp, 0.0f);   // read back the total
            out[0] = tot * (float)(1.0 / ((double)OW * (double)OH));
        }
    }
}

extern "C" void kernel_launch(void* const* d_in, const int* in_sizes, int n_in,
                              void* d_out, int out_size, void* d_ws, size_t ws_size,
                              hipStream_t stream)
{
    const float* O = (const float*)d_in[0];
    const float* T = (const float*)d_in[1];
    float* out = (float*)d_out;
    float* acc = (float*)d_ws;
    unsigned* ctr = (unsigned*)d_ws + 1;

    hipMemsetAsync(d_ws, 0, 2 * sizeof(float), stream);  // ws re-poisoned 0xAA

    dim3 grid(GX, GY);   // (4, 228) = 912 blocks
    ssim_main<<<grid, NTHR, 0, stream>>>(O, T, acc, ctr, out);
}